// Round 8
// baseline (96.818 us; speedup 1.0000x reference)
//
#include <hip/hip_runtime.h>
#include <hip/hip_bf16.h>
#include <cstdint>

#define B_ 8
#define N_ 512
#define D_ 256
#define E_ 16384
#define H_ 256

#define SA_STRIDE 56
#define SB_STRIDE 56
#define NSB 8      // scatter sub-blocks
#define SUBCAP 32  // per-(block,src) capacity; Binom(2048,1/512)>=32 prob ~2e-17

using bf16x8 = __attribute__((ext_vector_type(8))) short;
using f32x4  = __attribute__((ext_vector_type(4))) float;

__device__ inline unsigned short f2bf(float f) {
    union { float f; unsigned u; } v; v.f = f;
    unsigned u = v.u;
    return (unsigned short)((u + 0x7fffu + ((u >> 16) & 1u)) >> 16);  // RNE
}

// blocks 0-31: transpose W1 halves -> W1T (512 n-rows x 256 k) bf16.
// blocks 32-39: edge scatter, ZERO global atomics: block sb owns edge slice
//   [2048*sb, 2048*(sb+1)); slot via LDS atomic; private sub-bucket per
//   (src, sb); counts via plain stores (block exclusively owns gCnt[*][sb]).
__global__ __launch_bounds__(256)
void prep_k(const float* __restrict__ W1, const int* __restrict__ eidx,
            unsigned short* __restrict__ W1T,
            int* __restrict__ gCnt, int* __restrict__ gBucket) {
    const int tb = blockIdx.x, t = threadIdx.x;

    if (tb >= 32) {
        __shared__ int hist[512];
        const int sb = tb - 32;
        for (int i = t; i < 512; i += 256) hist[i] = 0;
        __syncthreads();
#pragma unroll
        for (int k = 0; k < 8; k++) {
            int e = sb * 2048 + k * 256 + t;
            int s = eidx[e];
            int d = eidx[E_ + e];
            int slot = atomicAdd(&hist[s], 1);          // LDS atomic only
            gBucket[(s * NSB + sb) * SUBCAP + slot] = d;
        }
        __syncthreads();
        for (int s = t; s < 512; s += 256)
            gCnt[s * NSB + sb] = hist[s];               // plain store
        return;
    }

    __shared__ float tile[64][65];
    const int h   = tb >> 4;
    const int rem = tb & 15;
    const int tk  = (rem >> 2) * 64;
    const int tn  = (rem & 3) * 64;
    const float* Wh = W1 + (size_t)h * 256 * 256;
    const int c = t & 63, r0 = t >> 6;
#pragma unroll
    for (int i = 0; i < 16; i++) {
        int r = r0 + i * 4;
        tile[r][c] = Wh[(size_t)(tk + r) * 256 + tn + c];
    }
    __syncthreads();
#pragma unroll
    for (int i = 0; i < 16; i++) {
        int rn = r0 + i * 4;
        W1T[(size_t)(h * 256 + tn + rn) * 256 + tk + c] = f2bf(tile[c][rn]);
    }
}

// P (4096,512) bf16 = feat x [W1a|W1b], b1 folded into U half;
// also zeroes d_out (64 KB per block).
__global__ __launch_bounds__(256)
void node_gemm(const float* __restrict__ feat,
               const unsigned short* __restrict__ W1T,
               const float* __restrict__ b1,
               unsigned short* __restrict__ P,
               float4* __restrict__ out4) {
    __shared__ unsigned short sA[64 * SA_STRIDE];
    __shared__ unsigned short sB[256 * SB_STRIDE];

    const int t  = threadIdx.x;
    const int bm = blockIdx.x >> 1;
    const int bn = blockIdx.x & 1;
    const int m0 = bm * 64;

    {
        float4 z = make_float4(0.f, 0.f, 0.f, 0.f);
        float4* oz = out4 + (size_t)blockIdx.x * 4096 + t;
#pragma unroll
        for (int i = 0; i < 16; i++) oz[i * 256] = z;
    }

    const int arow = t >> 2;
    const int akg  = (t & 3) * 8;
    const float* pA = feat + (size_t)(m0 + arow) * 256;
    const unsigned short* pB = W1T + (size_t)(bn * 256 + t) * 256;

    const int wave = t >> 6, lane = t & 63, l15 = lane & 15, quad = lane >> 4;

    f32x4 acc[4][4];
#pragma unroll
    for (int rm = 0; rm < 4; rm++)
#pragma unroll
        for (int cn = 0; cn < 4; cn++)
            acc[rm][cn] = (f32x4){0.f, 0.f, 0.f, 0.f};

    for (int k0 = 0; k0 < 256; k0 += 32) {
        __syncthreads();
        {
            float4 lo = *(const float4*)(pA + k0 + akg);
            float4 hi = *(const float4*)(pA + k0 + akg + 4);
            union { bf16x8 v; unsigned short s[8]; } u;
            u.s[0] = f2bf(lo.x); u.s[1] = f2bf(lo.y); u.s[2] = f2bf(lo.z); u.s[3] = f2bf(lo.w);
            u.s[4] = f2bf(hi.x); u.s[5] = f2bf(hi.y); u.s[6] = f2bf(hi.z); u.s[7] = f2bf(hi.w);
            *(bf16x8*)(sA + arow * SA_STRIDE + akg) = u.v;
        }
        {
            const unsigned short* p = pB + k0;
            uint4 q0 = *(const uint4*)(p);
            uint4 q1 = *(const uint4*)(p + 8);
            uint4 q2 = *(const uint4*)(p + 16);
            uint4 q3 = *(const uint4*)(p + 24);
            *(uint4*)(sB + t * SB_STRIDE +  0) = q0;
            *(uint4*)(sB + t * SB_STRIDE +  8) = q1;
            *(uint4*)(sB + t * SB_STRIDE + 16) = q2;
            *(uint4*)(sB + t * SB_STRIDE + 24) = q3;
        }
        __syncthreads();

        bf16x8 af[4], bfr[4];
#pragma unroll
        for (int rm = 0; rm < 4; rm++)
            af[rm] = *(const bf16x8*)(sA + (rm * 16 + l15) * SA_STRIDE + quad * 8);
#pragma unroll
        for (int cn = 0; cn < 4; cn++)
            bfr[cn] = *(const bf16x8*)(sB + (wave * 64 + cn * 16 + l15) * SB_STRIDE + quad * 8);
#pragma unroll
        for (int rm = 0; rm < 4; rm++)
#pragma unroll
            for (int cn = 0; cn < 4; cn++)
                acc[rm][cn] = __builtin_amdgcn_mfma_f32_16x16x32_bf16(af[rm], bfr[cn], acc[rm][cn], 0, 0, 0);
    }

#pragma unroll
    for (int cn = 0; cn < 4; cn++) {
        int colh = wave * 64 + cn * 16 + l15;
        float bias = (bn == 0) ? b1[colh] : 0.f;
        int col = bn * 256 + colh;
#pragma unroll
        for (int rm = 0; rm < 4; rm++)
#pragma unroll
            for (int r = 0; r < 4; r++) {
                int row = m0 + rm * 16 + quad * 4 + r;
                P[(size_t)row * 512 + col] = f2bf(acc[rm][cn][r] + bias);
            }
    }
}

// 8 bf16 (u,v) pairs -> partial relu-dot (b1 already folded into u)
__device__ inline float dot8nb(uint4 qu, uint4 qv, const float* w2p) {
    unsigned us[4] = {qu.x, qu.y, qu.z, qu.w};
    unsigned vs[4] = {qv.x, qv.y, qv.z, qv.w};
    float p = 0.f;
#pragma unroll
    for (int j = 0; j < 4; j++) {
        float ulo = __uint_as_float(us[j] << 16);
        float uhi = __uint_as_float(us[j] & 0xffff0000u);
        float vlo = __uint_as_float(vs[j] << 16);
        float vhi = __uint_as_float(vs[j] & 0xffff0000u);
        float hlo = fmaxf(ulo + vlo, 0.f);
        float hhi = fmaxf(uhi + vhi, 0.f);
        p = fmaf(hlo, w2p[2 * j],     p);
        p = fmaf(hhi, w2p[2 * j + 1], p);
    }
    return p;
}

// Bucketed edge scoring over 8 sub-buckets per src (register prefix walk).
__global__ __launch_bounds__(256)
void edge_score(const unsigned short* __restrict__ P,
                const float* __restrict__ W2, const float* __restrict__ b2,
                const int* __restrict__ gCnt, const int* __restrict__ gBucket,
                float* __restrict__ out) {
    const int b     = blockIdx.x & 7;          // XCD-aware batch mapping
    const int chunk = blockIdx.x >> 3;         // 0..255 -> srcs {2c, 2c+1}
    const int lane  = threadIdx.x & 63;
    const int wave  = threadIdx.x >> 6;
    const int g     = lane >> 4;
    const int w     = lane & 15;
    const int wid   = wave * 4 + g;            // 0..15
    const int s     = 2 * chunk + (wid >> 3);  // bucket src
    const int o     = wid & 7;                 // worker offset in bucket

    const int* cp = gCnt + s * NSB;
    int4 c0 = *(const int4*)cp;
    int4 c1 = *(const int4*)(cp + 4);
    int pre[9];
    pre[0] = 0;
    pre[1] = pre[0] + c0.x; pre[2] = pre[1] + c0.y;
    pre[3] = pre[2] + c0.z; pre[4] = pre[3] + c0.w;
    pre[5] = pre[4] + c1.x; pre[6] = pre[5] + c1.y;
    pre[7] = pre[6] + c1.z; pre[8] = pre[7] + c1.w;
    const int en = pre[8];
    const int* bucket = gBucket + s * (NSB * SUBCAP);

    float w2r[16];
#pragma unroll
    for (int j = 0; j < 4; j++)
        *(float4*)(w2r + 4 * j) = *(const float4*)(W2 + w * 16 + 4 * j);
    const float b2v = b2[0];

    const unsigned short* Pu = P + ((size_t)b * 512 + s) * 512 + w * 16;
    uint4 u0 = *(const uint4*)(Pu);
    uint4 u1 = *(const uint4*)(Pu + 8);
    const unsigned short* Pv = P + (size_t)b * 512 * 512 + 256 + w * 16;
    float* outb = out + ((size_t)b * 512 + s) * 512;

    // map concatenated index j -> sub-bucket slot
    auto fetch = [&](int j) -> int {
        int i = 0;
#pragma unroll
        for (int q = 1; q < 8; q++) i += (j >= pre[q]);
        return bucket[i * SUBCAP + (j - pre[i])];
    };

    int j = o;
    int dst0 = 0; uint4 v00 = {}, v01 = {};
    if (j < en) {
        dst0 = fetch(j);
        const unsigned short* pv = Pv + (size_t)dst0 * 512;
        v00 = *(const uint4*)pv; v01 = *(const uint4*)(pv + 8);
    }
    while (j < en) {
        int jn = j + 8;
        int dst1 = 0; uint4 v10 = {}, v11 = {};
        if (jn < en) {
            dst1 = fetch(jn);
            const unsigned short* pv = Pv + (size_t)dst1 * 512;
            v10 = *(const uint4*)pv; v11 = *(const uint4*)(pv + 8);
        }
        float p = dot8nb(u0, v00, w2r) + dot8nb(u1, v01, w2r + 8);
        p += __shfl_xor(p, 1);
        p += __shfl_xor(p, 2);
        p += __shfl_xor(p, 4);
        p += __shfl_xor(p, 8);
        if (w == 0) {
            float sv = 1.0f / (1.0f + __expf(-(p + b2v)));
            outb[dst0] = sv;
        }
        dst0 = dst1; v00 = v10; v01 = v11; j = jn;
    }
}

extern "C" void kernel_launch(void* const* d_in, const int* in_sizes, int n_in,
                              void* d_out, int out_size, void* d_ws, size_t ws_size,
                              hipStream_t stream) {
    const float* feat = (const float*)d_in[0];
    const float* W1   = (const float*)d_in[1];
    const float* b1   = (const float*)d_in[2];
    const float* W2   = (const float*)d_in[3];
    const float* b2   = (const float*)d_in[4];
    const int*   eidx = (const int*)d_in[5];
    float* out = (float*)d_out;

    unsigned short* W1T = (unsigned short*)d_ws;                        // 256 KB
    unsigned short* P   = (unsigned short*)((char*)d_ws + (1 << 20));   // 4 MB
    int* gCnt    = (int*)((char*)d_ws + (6 << 20));                     // 16 KB
    int* gBucket = (int*)((char*)d_ws + (6 << 20) + (1 << 16));         // 512 KB

    prep_k<<<40, 256, 0, stream>>>(W1, eidx, W1T, gCnt, gBucket);
    node_gemm<<<128, 256, 0, stream>>>(feat, W1T, b1, P, (float4*)out);
    edge_score<<<2048, 256, 0, stream>>>(P, W2, b2, gCnt, gBucket, out);
}

// Round 11
// 94.642 us; speedup vs baseline: 1.0230x; 1.0230x over previous
//
#include <hip/hip_runtime.h>
#include <hip/hip_bf16.h>
#include <cstdint>

#define B_ 8
#define N_ 512
#define D_ 256
#define E_ 16384
#define H_ 256

#define SA_STRIDE 56
#define SB_STRIDE 56

using bf16x8 = __attribute__((ext_vector_type(8))) short;
using bf16x4 = __attribute__((ext_vector_type(4))) short;
using f32x4  = __attribute__((ext_vector_type(4))) float;

__device__ inline unsigned short f2bf(float f) {
    union { float f; unsigned u; } v; v.f = f;
    unsigned u = v.u;
    return (unsigned short)((u + 0x7fffu + ((u >> 16) & 1u)) >> 16);  // RNE
}

__global__ __launch_bounds__(256)
void zero_cnt(int* __restrict__ gCount) {
    gCount[threadIdx.x] = 0;
    gCount[threadIdx.x + 256] = 0;
}

// blocks 0-31: transpose W1 halves -> W1T (512 n-rows x 256 k) bf16.
// blocks 32-39: LDS-aggregated bucket scatter (LDS hist slot + one global
//   atomicAdd per (block,src) range reservation). gCount is zeroed by the
//   preceding zero_cnt dispatch — no in-grid zeroing (R10's race).
__global__ __launch_bounds__(256)
void prep_k(const float* __restrict__ W1, const int* __restrict__ eidx,
            unsigned short* __restrict__ W1T,
            int* __restrict__ gCount, int* __restrict__ gBucket) {
    const int tb = blockIdx.x, t = threadIdx.x;

    if (tb >= 32) {
        __shared__ int hist[512];
        __shared__ int base[512];
        const int sb = tb - 32;
        int mysrc[8], mydst[8], myslot[8];
        for (int i = t; i < 512; i += 256) hist[i] = 0;
        __syncthreads();
#pragma unroll
        for (int i = 0; i < 8; i++) {
            int e = sb * 2048 + i * 256 + t;
            mysrc[i] = eidx[e];
            mydst[i] = eidx[E_ + e];
            myslot[i] = atomicAdd(&hist[mysrc[i]], 1);
        }
        __syncthreads();
        for (int i = t; i < 512; i += 256) {
            int c = hist[i];
            base[i] = c ? atomicAdd(&gCount[i], c) : 0;
        }
        __syncthreads();
#pragma unroll
        for (int i = 0; i < 8; i++)
            gBucket[(mysrc[i] << 7) + base[mysrc[i]] + myslot[i]] = mydst[i];
        return;
    }

    __shared__ float tile[64][65];
    const int h   = tb >> 4;
    const int rem = tb & 15;
    const int tk  = (rem >> 2) * 64;
    const int tn  = (rem & 3) * 64;
    const float* Wh = W1 + (size_t)h * 256 * 256;
    const int c = t & 63, r0 = t >> 6;
#pragma unroll
    for (int i = 0; i < 16; i++) {
        int r = r0 + i * 4;
        tile[r][c] = Wh[(size_t)(tk + r) * 256 + tn + c];
    }
    __syncthreads();
#pragma unroll
    for (int i = 0; i < 16; i++) {
        int rn = r0 + i * 4;
        W1T[(size_t)(h * 256 + tn + rn) * 256 + tk + c] = f2bf(tile[c][rn]);
    }
}

// P (4096,512) bf16 = feat x [W1a|W1b], b1 folded into U half.
// M-tile 32 -> 256 blocks, all CUs engaged. Also zeroes d_out (32 KB/block).
__global__ __launch_bounds__(256)
void node_gemm(const float* __restrict__ feat,
               const unsigned short* __restrict__ W1T,
               const float* __restrict__ b1,
               unsigned short* __restrict__ P,
               float4* __restrict__ out4) {
    __shared__ unsigned short sA[32 * SA_STRIDE];
    __shared__ unsigned short sB[256 * SB_STRIDE];

    const int t  = threadIdx.x;
    const int bm = blockIdx.x >> 1;
    const int bn = blockIdx.x & 1;
    const int m0 = bm * 32;

    {   // zero 32 KB of out: 2048 float4 per block (256 blocks x 2048 = 8 MB)
        float4 z = make_float4(0.f, 0.f, 0.f, 0.f);
        float4* oz = out4 + (size_t)blockIdx.x * 2048 + t;
#pragma unroll
        for (int i = 0; i < 8; i++) oz[i * 256] = z;
    }

    const int arow = t >> 3;          // 32 rows, 8 threads/row
    const int akg  = (t & 7) * 4;     // 4 fp32 each
    const float* pA = feat + (size_t)(m0 + arow) * 256;
    const unsigned short* pB = W1T + (size_t)(bn * 256 + t) * 256;

    const int wave = t >> 6, lane = t & 63, l15 = lane & 15, quad = lane >> 4;

    f32x4 acc[2][4];
#pragma unroll
    for (int rm = 0; rm < 2; rm++)
#pragma unroll
        for (int cn = 0; cn < 4; cn++)
            acc[rm][cn] = (f32x4){0.f, 0.f, 0.f, 0.f};

    for (int k0 = 0; k0 < 256; k0 += 32) {
        __syncthreads();
        {
            float4 lo = *(const float4*)(pA + k0 + akg);
            union { bf16x4 v; unsigned short s[4]; } u;
            u.s[0] = f2bf(lo.x); u.s[1] = f2bf(lo.y);
            u.s[2] = f2bf(lo.z); u.s[3] = f2bf(lo.w);
            *(bf16x4*)(sA + arow * SA_STRIDE + akg) = u.v;
        }
        {
            const unsigned short* p = pB + k0;
            uint4 q0 = *(const uint4*)(p);
            uint4 q1 = *(const uint4*)(p + 8);
            uint4 q2 = *(const uint4*)(p + 16);
            uint4 q3 = *(const uint4*)(p + 24);
            *(uint4*)(sB + t * SB_STRIDE +  0) = q0;
            *(uint4*)(sB + t * SB_STRIDE +  8) = q1;
            *(uint4*)(sB + t * SB_STRIDE + 16) = q2;
            *(uint4*)(sB + t * SB_STRIDE + 24) = q3;
        }
        __syncthreads();

        bf16x8 af[2], bfr[4];
#pragma unroll
        for (int rm = 0; rm < 2; rm++)
            af[rm] = *(const bf16x8*)(sA + (rm * 16 + l15) * SA_STRIDE + quad * 8);
#pragma unroll
        for (int cn = 0; cn < 4; cn++)
            bfr[cn] = *(const bf16x8*)(sB + (wave * 64 + cn * 16 + l15) * SB_STRIDE + quad * 8);
#pragma unroll
        for (int rm = 0; rm < 2; rm++)
#pragma unroll
            for (int cn = 0; cn < 4; cn++)
                acc[rm][cn] = __builtin_amdgcn_mfma_f32_16x16x32_bf16(af[rm], bfr[cn], acc[rm][cn], 0, 0, 0);
    }

#pragma unroll
    for (int cn = 0; cn < 4; cn++) {
        int colh = wave * 64 + cn * 16 + l15;
        float bias = (bn == 0) ? b1[colh] : 0.f;
        int col = bn * 256 + colh;
#pragma unroll
        for (int rm = 0; rm < 2; rm++)
#pragma unroll
            for (int r = 0; r < 4; r++) {
                int row = m0 + rm * 16 + quad * 4 + r;
                P[(size_t)row * 512 + col] = f2bf(acc[rm][cn][r] + bias);
            }
    }
}

// 8 bf16 (u,v) pairs -> partial relu-dot (b1 already folded into u)
__device__ inline float dot8nb(uint4 qu, uint4 qv, const float* w2p) {
    unsigned us[4] = {qu.x, qu.y, qu.z, qu.w};
    unsigned vs[4] = {qv.x, qv.y, qv.z, qv.w};
    float p = 0.f;
#pragma unroll
    for (int j = 0; j < 4; j++) {
        float ulo = __uint_as_float(us[j] << 16);
        float uhi = __uint_as_float(us[j] & 0xffff0000u);
        float vlo = __uint_as_float(vs[j] << 16);
        float vhi = __uint_as_float(vs[j] & 0xffff0000u);
        float hlo = fmaxf(ulo + vlo, 0.f);
        float hhi = fmaxf(uhi + vhi, 0.f);
        p = fmaf(hlo, w2p[2 * j],     p);
        p = fmaf(hhi, w2p[2 * j + 1], p);
    }
    return p;
}

// Bucketed edge scoring: 16-lane worker owns (src, offset o); U'[src]
// register-resident, streams V[dst], 2-stage pipeline, 8 workers/bucket.
__global__ __launch_bounds__(256)
void edge_score(const unsigned short* __restrict__ P,
                const float* __restrict__ W2, const float* __restrict__ b2,
                const int* __restrict__ gCount, const int* __restrict__ gBucket,
                float* __restrict__ out) {
    const int b     = blockIdx.x & 7;          // XCD-aware batch mapping
    const int chunk = blockIdx.x >> 3;         // 0..255 -> srcs {2c, 2c+1}
    const int lane  = threadIdx.x & 63;
    const int wave  = threadIdx.x >> 6;
    const int g     = lane >> 4;
    const int w     = lane & 15;
    const int wid   = wave * 4 + g;            // 0..15
    const int s     = 2 * chunk + (wid >> 3);  // bucket src
    const int o     = wid & 7;                 // worker offset in bucket

    const int en = gCount[s];
    const int* bucket = gBucket + (s << 7);

    float w2r[16];
#pragma unroll
    for (int j = 0; j < 4; j++)
        *(float4*)(w2r + 4 * j) = *(const float4*)(W2 + w * 16 + 4 * j);
    const float b2v = b2[0];

    const unsigned short* Pu = P + ((size_t)b * 512 + s) * 512 + w * 16;
    uint4 u0 = *(const uint4*)(Pu);
    uint4 u1 = *(const uint4*)(Pu + 8);
    const unsigned short* Pv = P + (size_t)b * 512 * 512 + 256 + w * 16;
    float* outb = out + ((size_t)b * 512 + s) * 512;

    int j = o;
    int dst0 = 0; uint4 v00 = {}, v01 = {};
    if (j < en) {
        dst0 = bucket[j];
        const unsigned short* pv = Pv + (size_t)dst0 * 512;
        v00 = *(const uint4*)pv; v01 = *(const uint4*)(pv + 8);
    }
    while (j < en) {
        int jn = j + 8;
        int dst1 = 0; uint4 v10 = {}, v11 = {};
        if (jn < en) {
            dst1 = bucket[jn];
            const unsigned short* pv = Pv + (size_t)dst1 * 512;
            v10 = *(const uint4*)pv; v11 = *(const uint4*)(pv + 8);
        }
        float p = dot8nb(u0, v00, w2r) + dot8nb(u1, v01, w2r + 8);
        p += __shfl_xor(p, 1);
        p += __shfl_xor(p, 2);
        p += __shfl_xor(p, 4);
        p += __shfl_xor(p, 8);
        if (w == 0) {
            float sv = 1.0f / (1.0f + __expf(-(p + b2v)));
            outb[dst0] = sv;
        }
        dst0 = dst1; v00 = v10; v01 = v11; j = jn;
    }
}

extern "C" void kernel_launch(void* const* d_in, const int* in_sizes, int n_in,
                              void* d_out, int out_size, void* d_ws, size_t ws_size,
                              hipStream_t stream) {
    const float* feat = (const float*)d_in[0];
    const float* W1   = (const float*)d_in[1];
    const float* b1   = (const float*)d_in[2];
    const float* W2   = (const float*)d_in[3];
    const float* b2   = (const float*)d_in[4];
    const int*   eidx = (const int*)d_in[5];
    float* out = (float*)d_out;

    unsigned short* W1T = (unsigned short*)d_ws;                        // 256 KB
    unsigned short* P   = (unsigned short*)((char*)d_ws + (1 << 20));   // 4 MB
    int* gCount  = (int*)((char*)d_ws + (6 << 20));                     // 2 KB
    int* gBucket = (int*)((char*)d_ws + (6 << 20) + 4096);              // 256 KB

    zero_cnt<<<1, 256, 0, stream>>>(gCount);
    prep_k<<<40, 256, 0, stream>>>(W1, eidx, W1T, gCount, gBucket);
    node_gemm<<<256, 256, 0, stream>>>(feat, W1T, b1, P, (float4*)out);
    edge_score<<<2048, 256, 0, stream>>>(P, W2, b2, gCount, gBucket, out);
}